// Round 1
// baseline (273.459 us; speedup 1.0000x reference)
//
#include <hip/hip_runtime.h>
#include <stdint.h>

typedef short v8s __attribute__((ext_vector_type(8)));
typedef float v4f __attribute__((ext_vector_type(4)));

#define N_EMBD 1024
#define HEAD 128
#define TOKENS 16384   // 8*2048
#define T_SEQ 2048
#define BATCH 8

__device__ __forceinline__ short f2bf(float f) {
    union { float f; uint32_t u; } c; c.f = f;
    uint32_t u = c.u;
    uint32_t r = (u + 0x7fffu + ((u >> 16) & 1u)) >> 16;
    return (short)r;
}

// ---------------- kernel 1: W transpose + bf16 convert ----------------
// wt[w][h][c] (bf16) <- W_w[c][h] (fp32), w: 0=q,1=k,2=v
__global__ __launch_bounds__(256)
void wt_kernel(const float* __restrict__ Wq, const float* __restrict__ Wk,
               const float* __restrict__ Wv, short* __restrict__ wt) {
    int tid = blockIdx.x * 256 + threadIdx.x;       // 0 .. 3*131072-1
    int w   = tid >> 17;
    int rem = tid & 131071;                          // c*128 + h
    int c = rem >> 7, h = rem & 127;
    const float* src = (w == 0) ? Wq : ((w == 1) ? Wk : Wv);
    wt[w * 131072 + h * 1024 + c] = f2bf(src[rem]);
}

// ---------------- kernel 2: QKV projection GEMM ----------------
// qkv[w] = x (fp32->bf16) @ Wt[w]^T ; out bf16 [16384][128] per w
__global__ __launch_bounds__(256)
void qkv_gemm(const float* __restrict__ x, const short* __restrict__ wt,
              short* __restrict__ qkv) {
    const int w  = blockIdx.x;       // 0..2 (fastest -> 3 blocks share x tile in L2)
    const int mt = blockIdx.y;       // 0..127
    const int m0 = mt * 128;

    __shared__ short sA[128 * 40];   // 128 rows x 32 k, stride 40 (pad)
    __shared__ short sB[128 * 40];   // 128 n-rows x 32 k, stride 40

    const int t = threadIdx.x;
    const int wv = t >> 6, lane = t & 63, ln = lane & 15, qd = lane >> 4;
    const int wm = wv & 1, wn = wv >> 1;

    v4f acc[4][4] = {};
    const short* wtw = wt + w * 131072;

    for (int kk = 0; kk < 1024; kk += 32) {
        __syncthreads();
        // stage A: 128x32 fp32 -> bf16
        for (int it = 0; it < 4; ++it) {
            int pos = it * 256 + t;           // float4 chunk id, 0..1023
            int row = pos >> 3, c4 = pos & 7;
            const float4 f = *(const float4*)(x + (size_t)(m0 + row) * 1024 + kk + c4 * 4);
            union { short4 v; short s[4]; } pk;
            pk.s[0] = f2bf(f.x); pk.s[1] = f2bf(f.y);
            pk.s[2] = f2bf(f.z); pk.s[3] = f2bf(f.w);
            *(short4*)(&sA[row * 40 + c4 * 4]) = pk.v;
        }
        // stage B: Wt rows (n) x 32 k, bf16 direct
        for (int it = 0; it < 2; ++it) {
            int pos = it * 256 + t;           // 16B chunk id, 0..511
            int row = pos >> 2, c8 = pos & 3;
            uint4 d = *(const uint4*)(wtw + row * 1024 + kk + c8 * 8);
            *(uint4*)(&sB[row * 40 + c8 * 8]) = d;
        }
        __syncthreads();

        v8s a[4], b[4];
        for (int mi = 0; mi < 4; ++mi)
            a[mi] = *(const v8s*)&sA[(wm * 64 + mi * 16 + ln) * 40 + qd * 8];
        for (int ni = 0; ni < 4; ++ni)
            b[ni] = *(const v8s*)&sB[(wn * 64 + ni * 16 + ln) * 40 + qd * 8];
        for (int mi = 0; mi < 4; ++mi)
            for (int ni = 0; ni < 4; ++ni)
                acc[mi][ni] = __builtin_amdgcn_mfma_f32_16x16x32_bf16(a[mi], b[ni], acc[mi][ni], 0, 0, 0);
    }

    short* outw = qkv + (size_t)w * TOKENS * HEAD;
    for (int mi = 0; mi < 4; ++mi)
        for (int ni = 0; ni < 4; ++ni)
            for (int r = 0; r < 4; ++r) {
                int row = m0 + wm * 64 + mi * 16 + qd * 4 + r;
                int col = wn * 64 + ni * 16 + ln;
                outw[(size_t)row * HEAD + col] = f2bf(acc[mi][ni][r]);
            }
}

// ---------------- kernel 3: flash attention (causal) ----------------
__global__ __launch_bounds__(256)
void attn_kernel(const short* __restrict__ qb, const short* __restrict__ kb,
                 const short* __restrict__ vb, float* __restrict__ out) {
    const int bid = blockIdx.x;
    const int b = bid >> 5, qt = bid & 31;      // 32 q-tiles of 64
    const int q0 = qt * 64;

    __shared__ short sK[64 * 136];    // K rows x 128 d, stride 136
    __shared__ short sVt[128 * 72];   // V^T: d x 64 keys, stride 72
    __shared__ short sP[64 * 72];     // P: 64 q x 64 keys, stride 72

    const int t = threadIdx.x;
    const int wv = t >> 6, lane = t & 63, ln = lane & 15, qd = lane >> 4;

    // Q fragments held in registers for the whole block
    const short* qrow = qb + ((size_t)(b * T_SEQ + q0 + wv * 16 + ln)) * HEAD;
    v8s qf[4];
    for (int ks = 0; ks < 4; ++ks)
        qf[ks] = *(const v8s*)(qrow + ks * 32 + qd * 8);

    v4f o[8] = {};
    float m2[4] = {-INFINITY, -INFINITY, -INFINITY, -INFINITY};
    float l[4]  = {0.f, 0.f, 0.f, 0.f};
    const float sc = 1.4426950408889634f / 11.313708498984761f;  // log2e / sqrt(128)

    for (int kt = 0; kt <= qt; ++kt) {
        __syncthreads();   // protect LDS staging vs previous iteration reads
        // stage K tile [64][128]
        const short* kbase = kb + ((size_t)(b * T_SEQ + kt * 64)) * HEAD;
        for (int it = 0; it < 4; ++it) {
            int c = it * 256 + t;               // 16B chunk id, 0..1023
            int row = c >> 4, c8 = c & 15;
            uint4 d = *(const uint4*)(kbase + row * HEAD + c8 * 8);
            *(uint4*)(&sK[row * 136 + c8 * 8]) = d;
        }
        // stage V tile transposed: sVt[d][key]
        const short* vbase = vb + ((size_t)(b * T_SEQ + kt * 64)) * HEAD;
        {
            int key = t & 63;
            int wvi = t >> 6;
            for (int it = 0; it < 4; ++it) {
                int col8 = it * 4 + wvi;        // d-chunk 0..15
                union { uint4 u; short s[8]; } tv;
                tv.u = *(const uint4*)(vbase + key * HEAD + col8 * 8);
                for (int j = 0; j < 8; ++j)
                    sVt[(col8 * 8 + j) * 72 + key] = tv.s[j];
            }
        }
        __syncthreads();

        // S = Q K^T  (wave handles 16 q-rows x 64 keys)
        v4f s[4] = {};
        for (int ni = 0; ni < 4; ++ni)
            for (int ks = 0; ks < 4; ++ks) {
                v8s kf = *(const v8s*)&sK[(ni * 16 + ln) * 136 + ks * 32 + qd * 8];
                s[ni] = __builtin_amdgcn_mfma_f32_16x16x32_bf16(qf[ks], kf, s[ni], 0, 0, 0);
            }

        // scale (log2-units) + causal mask on diagonal tile
        const bool diag = (kt == qt);
        float sv[4][4];
        for (int ni = 0; ni < 4; ++ni)
            for (int r = 0; r < 4; ++r) {
                float v = s[ni][r] * sc;
                if (diag) {
                    int kg = ni * 16 + ln;
                    int qg = wv * 16 + qd * 4 + r;
                    if (kg > qg) v = -INFINITY;
                }
                sv[ni][r] = v;
            }

        // online softmax: row max across 64 keys (16 lanes of quad x 4 subtiles)
        float alpha[4];
        for (int r = 0; r < 4; ++r) {
            float mm = fmaxf(fmaxf(sv[0][r], sv[1][r]), fmaxf(sv[2][r], sv[3][r]));
            mm = fmaxf(mm, __shfl_xor(mm, 1));
            mm = fmaxf(mm, __shfl_xor(mm, 2));
            mm = fmaxf(mm, __shfl_xor(mm, 4));
            mm = fmaxf(mm, __shfl_xor(mm, 8));
            float mn = fmaxf(m2[r], mm);
            alpha[r] = exp2f(m2[r] - mn);       // exp2(-inf)=0 on first tile
            m2[r] = mn;
        }

        // P = exp2(sv - m), write to sP (A-operand layout), accumulate row sums
        float rs[4] = {0.f, 0.f, 0.f, 0.f};
        for (int ni = 0; ni < 4; ++ni)
            for (int r = 0; r < 4; ++r) {
                float p = exp2f(sv[ni][r] - m2[r]);
                rs[r] += p;
                sP[(wv * 16 + qd * 4 + r) * 72 + ni * 16 + ln] = f2bf(p);
            }
        for (int r = 0; r < 4; ++r) {
            rs[r] += __shfl_xor(rs[r], 1);
            rs[r] += __shfl_xor(rs[r], 2);
            rs[r] += __shfl_xor(rs[r], 4);
            rs[r] += __shfl_xor(rs[r], 8);
            l[r] = l[r] * alpha[r] + rs[r];
        }
        // rescale O
        for (int oni = 0; oni < 8; ++oni)
            for (int r = 0; r < 4; ++r)
                o[oni][r] *= alpha[r];

        __syncthreads();   // ensure sP visible (conservative; also orders vs staging)

        // O += P V   (A = own 16 q-rows of sP, B = sVt)
        for (int kk2 = 0; kk2 < 2; ++kk2) {
            v8s pf = *(const v8s*)&sP[(wv * 16 + ln) * 72 + kk2 * 32 + qd * 8];
            for (int oni = 0; oni < 8; ++oni) {
                v8s vf = *(const v8s*)&sVt[(oni * 16 + ln) * 72 + kk2 * 32 + qd * 8];
                o[oni] = __builtin_amdgcn_mfma_f32_16x16x32_bf16(pf, vf, o[oni], 0, 0, 0);
            }
        }
    }

    // epilogue: normalize and store fp32
    float* ob = out + ((size_t)(b * T_SEQ + q0 + wv * 16)) * HEAD;
    for (int oni = 0; oni < 8; ++oni)
        for (int r = 0; r < 4; ++r)
            ob[(qd * 4 + r) * HEAD + oni * 16 + ln] = o[oni][r] / l[r];
}

extern "C" void kernel_launch(void* const* d_in, const int* in_sizes, int n_in,
                              void* d_out, int out_size, void* d_ws, size_t ws_size,
                              hipStream_t stream) {
    const float* x  = (const float*)d_in[0];
    const float* Wk = (const float*)d_in[1];
    const float* Wq = (const float*)d_in[2];
    const float* Wv = (const float*)d_in[3];
    float* out = (float*)d_out;

    char* ws = (char*)d_ws;
    short* wt  = (short*)ws;                          // 3*128*1024 bf16 = 768 KB
    short* qkv = (short*)(ws + (1 << 20));            // 3 * 16384*128 bf16 = 12 MB
    short* qb = qkv;
    short* kb = qkv + (size_t)TOKENS * HEAD;
    short* vb = qkv + (size_t)2 * TOKENS * HEAD;

    wt_kernel<<<1536, 256, 0, stream>>>(Wq, Wk, Wv, wt);
    qkv_gemm<<<dim3(3, 128), 256, 0, stream>>>(x, wt, qkv);
    attn_kernel<<<256, 256, 0, stream>>>(qb, kb, vb, out);
}

// Round 2
// 205.395 us; speedup vs baseline: 1.3314x; 1.3314x over previous
//
#include <hip/hip_runtime.h>
#include <stdint.h>

typedef short v8s __attribute__((ext_vector_type(8)));
typedef float v4f __attribute__((ext_vector_type(4)));

#define N_EMBD 1024
#define HEAD 128
#define TOKENS 16384   // 8*2048
#define T_SEQ 2048
#define BATCH 8
#define SPB 144        // split-blocks per batch: sum_{qt=0}^{31} (qt/4+1)

__device__ __forceinline__ short f2bf(float f) {
    union { float f; uint32_t u; } c; c.f = f;
    uint32_t u = c.u;
    uint32_t r = (u + 0x7fffu + ((u >> 16) & 1u)) >> 16;
    return (short)r;
}

__device__ __forceinline__ float bf2f(short s) {
    union { uint32_t u; float f; } c; c.u = ((uint32_t)(uint16_t)s) << 16;
    return c.f;
}

// ---------------- kernel 1: W transpose + bf16 convert ----------------
// wt[w][h][c] (bf16) <- W_w[c][h] (fp32), w: 0=q,1=k,2=v
__global__ __launch_bounds__(256)
void wt_kernel(const float* __restrict__ Wq, const float* __restrict__ Wk,
               const float* __restrict__ Wv, short* __restrict__ wt) {
    int tid = blockIdx.x * 256 + threadIdx.x;
    int w   = tid >> 17;
    int rem = tid & 131071;                          // c*128 + h
    int c = rem >> 7, h = rem & 127;
    const float* src = (w == 0) ? Wq : ((w == 1) ? Wk : Wv);
    wt[w * 131072 + h * 1024 + c] = f2bf(src[rem]);
}

// ---------------- kernel 2: QKV projection GEMM ----------------
// q,k: [token][d] bf16.  v: written TRANSPOSED as vT[d][token] bf16.
// BM=64 tile -> 3*256 = 768 blocks (3/CU) for latency hiding.
__global__ __launch_bounds__(256)
void qkv_gemm(const float* __restrict__ x, const short* __restrict__ wt,
              short* __restrict__ qkv, short* __restrict__ vT) {
    const int w  = blockIdx.x;       // 0..2 (fastest: 3 blocks share the x tile in L2)
    const int mt = blockIdx.y;       // 0..255
    const int m0 = mt * 64;

    __shared__ short smem[128 * 72];     // 18432 B; aliased: sA(64*40)+sB(128*40) | sT(128*72)
    short* sA = smem;                    // 64 rows x 32 k, stride 40
    short* sB = smem + 64 * 40;          // 128 n-rows x 32 k, stride 40

    const int t = threadIdx.x;
    const int wv = t >> 6, lane = t & 63, ln = lane & 15, qd = lane >> 4;
    const int wm = wv & 1, wn = wv >> 1;

    v4f acc[2][4] = {};
    const short* wtw = wt + w * 131072;

    for (int kk = 0; kk < 1024; kk += 32) {
        __syncthreads();
        // stage A: 64x32 fp32 -> bf16 (512 float4 chunks, 2/thread)
        for (int it = 0; it < 2; ++it) {
            int pos = it * 256 + t;
            int row = pos >> 3, c4 = pos & 7;
            const float4 f = *(const float4*)(x + (size_t)(m0 + row) * 1024 + kk + c4 * 4);
            union { short4 v; short s[4]; } pk;
            pk.s[0] = f2bf(f.x); pk.s[1] = f2bf(f.y);
            pk.s[2] = f2bf(f.z); pk.s[3] = f2bf(f.w);
            *(short4*)(&sA[row * 40 + c4 * 4]) = pk.v;
        }
        // stage B: 128x32 bf16 (512 16B chunks, 2/thread)
        for (int it = 0; it < 2; ++it) {
            int pos = it * 256 + t;
            int row = pos >> 2, c8 = pos & 3;
            uint4 d = *(const uint4*)(wtw + row * 1024 + kk + c8 * 8);
            *(uint4*)(&sB[row * 40 + c8 * 8]) = d;
        }
        __syncthreads();

        v8s a[2], b[4];
        for (int mi = 0; mi < 2; ++mi)
            a[mi] = *(const v8s*)&sA[(wm * 32 + mi * 16 + ln) * 40 + qd * 8];
        for (int ni = 0; ni < 4; ++ni)
            b[ni] = *(const v8s*)&sB[(wn * 64 + ni * 16 + ln) * 40 + qd * 8];
        for (int mi = 0; mi < 2; ++mi)
            for (int ni = 0; ni < 4; ++ni)
                acc[mi][ni] = __builtin_amdgcn_mfma_f32_16x16x32_bf16(a[mi], b[ni], acc[mi][ni], 0, 0, 0);
    }

    if (w < 2) {
        short* outw = qkv + (size_t)w * TOKENS * HEAD;
        for (int mi = 0; mi < 2; ++mi)
            for (int ni = 0; ni < 4; ++ni)
                for (int r = 0; r < 4; ++r) {
                    int row = m0 + wm * 32 + mi * 16 + qd * 4 + r;
                    int col = wn * 64 + ni * 16 + ln;
                    outw[(size_t)row * HEAD + col] = f2bf(acc[mi][ni][r]);
                }
    } else {
        // transpose tile through LDS -> coalesced vT[d][token] writes
        __syncthreads();
        short* sT = smem;   // [128 cols][stride 72], rows(=local tokens) 0..63
        for (int mi = 0; mi < 2; ++mi)
            for (int ni = 0; ni < 4; ++ni) {
                int col = wn * 64 + ni * 16 + ln;
                int row = wm * 32 + mi * 16 + qd * 4;     // 4 consecutive rows
                union { short s[4]; unsigned long long u; } pk;
                for (int r = 0; r < 4; ++r) pk.s[r] = f2bf(acc[mi][ni][r]);
                *(unsigned long long*)(&sT[col * 72 + row]) = pk.u;
            }
        __syncthreads();
        // 128 cols x 64 rows -> 1024 16B chunks, 4/thread
        for (int it = 0; it < 4; ++it) {
            int c = it * 256 + t;
            int col = c >> 3, c8 = c & 7;
            uint4 d = *(const uint4*)(&sT[col * 72 + c8 * 8]);
            *(uint4*)(&vT[(size_t)col * TOKENS + m0 + c8 * 8]) = d;
        }
    }
}

// ---------------- kernel 3: flash attention, split-K (causal) ----------------
// block = (b, qt, split); split covers up to 4 k-tiles of 64 keys.
// writes unnormalized O (bf16) + m,l (fp32) partials.
__global__ __launch_bounds__(256)
void attn_kernel(const short* __restrict__ qb, const short* __restrict__ kb,
                 const short* __restrict__ vT, short* __restrict__ po,
                 float* __restrict__ pm, float* __restrict__ pl) {
    const int bid = blockIdx.x;
    const int b = bid / SPB;
    const int r0 = bid % SPB;
    int qt = 0, acc0 = 0;
    for (;;) { int S = (qt >> 2) + 1; if (r0 < acc0 + S) break; acc0 += S; ++qt; }
    const int s = r0 - acc0;
    const int slot = bid;
    const int q0 = qt * 64;
    const int kt0 = s * 4;
    const int kt1 = (s * 4 + 4 < qt + 1) ? (s * 4 + 4) : (qt + 1);

    __shared__ short sK[64 * 136];    // K rows x 128 d, stride 136
    __shared__ short sVt[128 * 72];   // V^T: d x 64 keys, stride 72
    __shared__ short sP[64 * 72];     // P: 64 q x 64 keys, stride 72

    const int t = threadIdx.x;
    const int wv = t >> 6, lane = t & 63, ln = lane & 15, qd = lane >> 4;

    // Q fragments in registers for the whole block
    const short* qrow = qb + ((size_t)(b * T_SEQ + q0 + wv * 16 + ln)) * HEAD;
    v8s qf[4];
    for (int ks = 0; ks < 4; ++ks)
        qf[ks] = *(const v8s*)(qrow + ks * 32 + qd * 8);

    v4f o[8] = {};
    float m2[4] = {-INFINITY, -INFINITY, -INFINITY, -INFINITY};
    float l[4]  = {0.f, 0.f, 0.f, 0.f};
    const float sc = 1.4426950408889634f / 11.313708498984761f;  // log2e / sqrt(128)

    for (int kt = kt0; kt < kt1; ++kt) {
        __syncthreads();
        // stage K tile [64][128] (1024 16B chunks, 4/thread)
        const short* kbase = kb + ((size_t)(b * T_SEQ + kt * 64)) * HEAD;
        for (int it = 0; it < 4; ++it) {
            int c = it * 256 + t;
            int row = c >> 4, c8 = c & 15;
            uint4 d = *(const uint4*)(kbase + row * HEAD + c8 * 8);
            *(uint4*)(&sK[row * 136 + c8 * 8]) = d;
        }
        // stage V^T tile [128 d][64 keys] from pre-transposed vT (vectorized)
        const short* vbase = vT + (size_t)b * T_SEQ + kt * 64;
        for (int it = 0; it < 4; ++it) {
            int c = it * 256 + t;
            int row = c >> 3, c8 = c & 7;         // row = d, c8*8 = key chunk
            uint4 d = *(const uint4*)(vbase + (size_t)row * TOKENS + c8 * 8);
            *(uint4*)(&sVt[row * 72 + c8 * 8]) = d;
        }
        __syncthreads();

        // S = Q K^T  (wave: 16 q-rows x 64 keys)
        v4f sacc[4] = {};
        for (int ni = 0; ni < 4; ++ni)
            for (int ks = 0; ks < 4; ++ks) {
                v8s kf = *(const v8s*)&sK[(ni * 16 + ln) * 136 + ks * 32 + qd * 8];
                sacc[ni] = __builtin_amdgcn_mfma_f32_16x16x32_bf16(qf[ks], kf, sacc[ni], 0, 0, 0);
            }

        const bool diag = (kt == qt);
        float sv[4][4];
        for (int ni = 0; ni < 4; ++ni)
            for (int r = 0; r < 4; ++r) {
                float v = sacc[ni][r] * sc;
                if (diag) {
                    int kg = ni * 16 + ln;
                    int qg = wv * 16 + qd * 4 + r;
                    if (kg > qg) v = -INFINITY;
                }
                sv[ni][r] = v;
            }

        float alpha[4];
        for (int r = 0; r < 4; ++r) {
            float mm = fmaxf(fmaxf(sv[0][r], sv[1][r]), fmaxf(sv[2][r], sv[3][r]));
            mm = fmaxf(mm, __shfl_xor(mm, 1));
            mm = fmaxf(mm, __shfl_xor(mm, 2));
            mm = fmaxf(mm, __shfl_xor(mm, 4));
            mm = fmaxf(mm, __shfl_xor(mm, 8));
            float mn = fmaxf(m2[r], mm);
            alpha[r] = exp2f(m2[r] - mn);
            m2[r] = mn;
        }

        float rs[4] = {0.f, 0.f, 0.f, 0.f};
        for (int ni = 0; ni < 4; ++ni)
            for (int r = 0; r < 4; ++r) {
                float p = exp2f(sv[ni][r] - m2[r]);
                rs[r] += p;
                sP[(wv * 16 + qd * 4 + r) * 72 + ni * 16 + ln] = f2bf(p);
            }
        for (int r = 0; r < 4; ++r) {
            rs[r] += __shfl_xor(rs[r], 1);
            rs[r] += __shfl_xor(rs[r], 2);
            rs[r] += __shfl_xor(rs[r], 4);
            rs[r] += __shfl_xor(rs[r], 8);
            l[r] = l[r] * alpha[r] + rs[r];
        }
        for (int oni = 0; oni < 8; ++oni)
            for (int r = 0; r < 4; ++r)
                o[oni][r] *= alpha[r];

        __syncthreads();

        // O += P V
        for (int kk2 = 0; kk2 < 2; ++kk2) {
            v8s pf = *(const v8s*)&sP[(wv * 16 + ln) * 72 + kk2 * 32 + qd * 8];
            for (int oni = 0; oni < 8; ++oni) {
                v8s vf = *(const v8s*)&sVt[(oni * 16 + ln) * 72 + kk2 * 32 + qd * 8];
                o[oni] = __builtin_amdgcn_mfma_f32_16x16x32_bf16(pf, vf, o[oni], 0, 0, 0);
            }
        }
    }

    // epilogue: write partials (unnormalized)
    short* pob = po + (size_t)slot * 64 * 128;
    for (int oni = 0; oni < 8; ++oni)
        for (int r = 0; r < 4; ++r)
            pob[(wv * 16 + qd * 4 + r) * 128 + oni * 16 + ln] = f2bf(o[oni][r]);
    if (ln == 0)
        for (int r = 0; r < 4; ++r) {
            int row = wv * 16 + qd * 4 + r;
            pm[slot * 64 + row] = m2[r];
            pl[slot * 64 + row] = l[r];
        }
}

// ---------------- kernel 4: combine splits ----------------
__global__ __launch_bounds__(256)
void combine_kernel(const short* __restrict__ po, const float* __restrict__ pm,
                    const float* __restrict__ pl, float* __restrict__ out) {
    const int bid = blockIdx.x;          // b*32 + qt
    const int b = bid >> 5, qt = bid & 31;
    const int g = qt >> 2, rem = qt & 3;
    const int off = 2 * g * (g + 1) + rem * (g + 1);
    const int S = g + 1;
    const int base = b * SPB + off;
    const int t = threadIdx.x;
    const int row = t >> 2, d0 = (t & 3) * 32;

    float M = -INFINITY;
    for (int si = 0; si < S; ++si)
        M = fmaxf(M, pm[(base + si) * 64 + row]);

    float l = 0.f;
    float accv[32];
    for (int i = 0; i < 32; ++i) accv[i] = 0.f;
    for (int si = 0; si < S; ++si) {
        int slot = base + si;
        float wgt = exp2f(pm[slot * 64 + row] - M);
        l += wgt * pl[slot * 64 + row];
        const short* p = po + (size_t)slot * 8192 + row * 128 + d0;
        for (int c = 0; c < 4; ++c) {
            union { uint4 u; short s[8]; } v;
            v.u = *(const uint4*)(p + c * 8);
            for (int j = 0; j < 8; ++j)
                accv[c * 8 + j] += wgt * bf2f(v.s[j]);
        }
    }
    float inv = 1.f / l;
    float* ob = out + ((size_t)(b * T_SEQ) + qt * 64 + row) * HEAD + d0;
    for (int c = 0; c < 8; ++c) {
        float4 o4 = make_float4(accv[c * 4] * inv, accv[c * 4 + 1] * inv,
                                accv[c * 4 + 2] * inv, accv[c * 4 + 3] * inv);
        *(float4*)(ob + c * 4) = o4;
    }
}

extern "C" void kernel_launch(void* const* d_in, const int* in_sizes, int n_in,
                              void* d_out, int out_size, void* d_ws, size_t ws_size,
                              hipStream_t stream) {
    const float* x  = (const float*)d_in[0];
    const float* Wk = (const float*)d_in[1];
    const float* Wq = (const float*)d_in[2];
    const float* Wv = (const float*)d_in[3];
    float* out = (float*)d_out;

    char* ws = (char*)d_ws;
    short* wt  = (short*)ws;                              // 768 KB
    short* qkv = (short*)(ws + (1u << 20));               // q,k: 2 * 4 MB (v slot unused)
    short* qb  = qkv;
    short* kb  = qkv + (size_t)TOKENS * HEAD;
    short* vT  = (short*)(ws + 14680064u);                // 4 MB, [128][16384]
    short* po  = (short*)(ws + 18874368u);                // 1152*64*128 bf16 = 18 MB
    float* pm  = (float*)(ws + 37748736u);                // 1152*64 f32
    float* pl  = (float*)(ws + 38043648u);                // 1152*64 f32  (end ~38.3 MB)

    wt_kernel<<<1536, 256, 0, stream>>>(Wq, Wk, Wv, wt);
    qkv_gemm<<<dim3(3, 256), 256, 0, stream>>>(x, wt, qkv, vT);
    attn_kernel<<<BATCH * SPB, 256, 0, stream>>>(qb, kb, vT, po, pm, pl);
    combine_kernel<<<256, 256, 0, stream>>>(po, pm, pl, out);
}